// Round 3
// baseline (600.141 us; speedup 1.0000x reference)
//
#include <hip/hip_runtime.h>
#include <stdint.h>

// B = 1048576 rows, HID = 64. Residual MLP with training-mode BatchNorm.
// Recompute-fused layer kernels + bf16 activations (128 MB in d_ws).
// Round 3: persistent blocks (grid 2048 x 4 tiles of 128 rows), wave-private
// staging -> barrier-free tile loop, register-resident weight frags + BN
// consts, cross-tile global prefetch, register stats accumulation.
// MFMA 16x16x32 bf16 layouts (verified gfx950 mappings):
//   A: row = lane&15, k = (lane>>4)*8 + j   (16B contiguous -> b128)
//   B: col = lane&15, k = (lane>>4)*8 + j   (load from W^T, row-major)
//   C/D: col = lane&15, row = (lane>>4)*4 + reg

#define NROWS 1048576
#define EPS 1e-5f
#define INV_B 9.5367431640625e-07f  // 1/2^20 exact
#define LOG2E2 2.885390081777927f   // 2*log2(e)
#define TILES 4
#define BIGGRID 2048

typedef __attribute__((ext_vector_type(8))) short bfrag;   // 8 bf16 = 4 VGPR
typedef __attribute__((ext_vector_type(4))) float facc;    // MFMA C/D
typedef __attribute__((ext_vector_type(4))) float f4v;

__device__ __forceinline__ float bf2f(short s) {
  union { unsigned u; float f; } v;
  v.u = ((unsigned)(unsigned short)s) << 16;
  return v.f;
}
__device__ __forceinline__ short f2bf(float f) {
  union { float f; unsigned u; } v;
  v.f = f;
  unsigned r = v.u + 0x7FFFu + ((v.u >> 16) & 1u);  // RNE
  return (short)(r >> 16);
}
// tanh = 1 - 2/(e^{2x}+1); v_exp + v_rcp, saturates correctly at +-inf
__device__ __forceinline__ float tanh_fast(float x) {
  float e = __builtin_amdgcn_exp2f(x * LOG2E2);
  return 1.f - 2.f * __builtin_amdgcn_rcpf(e + 1.f);
}

// ---------------- reduce: P[nb][W] -> atomicAdd into S[W] ----------------
template <int W>
__global__ __launch_bounds__(256) void k_reduce(const float* __restrict__ P,
                                                float* __restrict__ S,
                                                int rows_per_blk) {
  __shared__ float red[256];
  const int tid = threadIdx.x;
  const int col = tid % W;
  const int grp = tid / W;
  const int G = 256 / W;
  size_t r0 = (size_t)blockIdx.x * rows_per_blk;
  float s = 0.f;
  for (int r = grp; r < rows_per_blk; r += G) s += P[(r0 + r) * W + col];
  red[tid] = s;
  __syncthreads();
  if (tid < W) {
    float t = 0.f;
#pragma unroll 4
    for (int g = 0; g < G; ++g) t += red[g * W + tid];
    atomicAdd(&S[tid], t);
  }
}

// ---------------- small kernels ----------------

__global__ __launch_bounds__(256) void k_stats_x(const float* __restrict__ x,
                                                 float* __restrict__ P) {
  __shared__ float red[4][8];
  const int tid = threadIdx.x;
  const int wave = tid >> 6;
  size_t base = (size_t)blockIdx.x * 1024 + tid;
  float s[4] = {0.f, 0.f, 0.f, 0.f}, q[4] = {0.f, 0.f, 0.f, 0.f};
#pragma unroll
  for (int it = 0; it < 4; ++it) {
    f4v v = *(const f4v*)(x + (base + (size_t)it * 256) * 4);
#pragma unroll
    for (int k = 0; k < 4; ++k) { s[k] += v[k]; q[k] = fmaf(v[k], v[k], q[k]); }
  }
#pragma unroll
  for (int off = 32; off > 0; off >>= 1) {
#pragma unroll
    for (int k = 0; k < 4; ++k) {
      s[k] += __shfl_xor(s[k], off);
      q[k] += __shfl_xor(q[k], off);
    }
  }
  if ((tid & 63) == 0) {
#pragma unroll
    for (int k = 0; k < 4; ++k) { red[wave][k] = s[k]; red[wave][4 + k] = q[k]; }
  }
  __syncthreads();
  if (tid < 8)
    P[blockIdx.x * 8 + tid] =
        red[0][tid] + red[1][tid] + red[2][tid] + red[3][tid];
}

__global__ __launch_bounds__(256) void k_stats_z1(
    const float* __restrict__ x, const float* __restrict__ bn0g,
    const float* __restrict__ bn0b, const float* __restrict__ W0,
    const float* __restrict__ b0, const float* __restrict__ sx,
    float* __restrict__ P) {
  __shared__ float red[2][4][64];
  const int tid = threadIdx.x;
  const int lane = tid & 63;
  const int wave = tid >> 6;
  int gw = blockIdx.x * 4 + wave;
  float sc[4], sh[4];
#pragma unroll
  for (int k = 0; k < 4; ++k) {
    float mean = sx[k] * INV_B;
    float var = fmaf(-mean, mean, sx[4 + k] * INV_B);
    float rs = rsqrtf(var + EPS);
    sc[k] = bn0g[k] * rs;
    sh[k] = fmaf(-sc[k], mean, bn0b[k]);
  }
  float w[4];
#pragma unroll
  for (int k = 0; k < 4; ++k) w[k] = W0[k * 64 + lane];
  float bj = b0[lane];
  float s = 0.f, q = 0.f;
  size_t r0 = (size_t)gw * 256;
  for (int r = 0; r < 256; ++r) {
    f4v xv = *(const f4v*)(x + (r0 + r) * 4);
    float acc = bj;
#pragma unroll
    for (int k = 0; k < 4; ++k)
      acc = fmaf(fmaf(xv[k], sc[k], sh[k]), w[k], acc);
    float z = tanh_fast(acc);
    s += z;
    q = fmaf(z, z, q);
  }
  red[0][wave][lane] = s;
  red[1][wave][lane] = q;
  __syncthreads();
  if (tid < 128) {
    int which = tid >> 6, c = tid & 63;
    P[blockIdx.x * 128 + tid] = red[which][0][c] + red[which][1][c] +
                                red[which][2][c] + red[which][3][c];
  }
}

__global__ __launch_bounds__(256) void k_prep(const float* __restrict__ Wh,
                                              short* __restrict__ WT) {
  int idx = blockIdx.x * 256 + threadIdx.x;  // 16384 total
  int l = idx >> 12, rem = idx & 4095, k = rem >> 6, c = rem & 63;
  WT[l * 4096 + c * 64 + k] = f2bf(Wh[l * 4096 + k * 64 + c]);
}

// ---------------- big fused kernels: 4 tiles x 128 rows per block ----------

// K_first: Y1 = BN(tanh(bn0(x)@W0+b0)), write Y1 bf16,
// partial stats of Z2 = tanh(Y1 @ W_hid0 + b_hid0) -> P[bid][128]
__global__ __launch_bounds__(256, 3) void k_first(
    const float* __restrict__ x, const float* __restrict__ bn0g,
    const float* __restrict__ bn0b, const float* __restrict__ W0,
    const float* __restrict__ b0, const float* __restrict__ gamma0,
    const float* __restrict__ beta0, const float* __restrict__ sx,
    const float* __restrict__ s1, const short* __restrict__ WTb,
    const float* __restrict__ bb, float* __restrict__ P,
    short* __restrict__ Y) {
  __shared__ __align__(16) float lds_x[128 * 4];
  __shared__ __align__(16) short lds_y[128 * 72];
  __shared__ float lds_st[128];

  const int tid = threadIdx.x;
  const int lane = tid & 63;
  const int wave = tid >> 6;
  const int l15 = lane & 15;
  const int q = lane >> 4;
  const int wr = wave * 32;

  if (tid < 128) lds_st[tid] = 0.f;
  // per-lane constants, all from global (L2-hot, tiny)
  float sc0[4], sh0[4];
#pragma unroll
  for (int k = 0; k < 4; ++k) {
    float mean = sx[k] * INV_B;
    float var = fmaf(-mean, mean, sx[4 + k] * INV_B);
    float rs = rsqrtf(var + EPS);
    sc0[k] = bn0g[k] * rs;
    sh0[k] = fmaf(-sc0[k], mean, bn0b[k]);
  }
  float w0c[4];
#pragma unroll
  for (int k = 0; k < 4; ++k) w0c[k] = W0[k * 64 + lane];
  float b0c = b0[lane];
  float mean1 = s1[lane] * INV_B;
  float var1 = fmaf(-mean1, mean1, s1[64 + lane] * INV_B);
  float A1c = gamma0[lane] * rsqrtf(var1 + EPS);
  float B1c = fmaf(-A1c, mean1, beta0[lane]);
  float bbv[4];
  bfrag bwb[4][2];
#pragma unroll
  for (int nt = 0; nt < 4; ++nt) {
    bbv[nt] = bb[nt * 16 + l15];
#pragma unroll
    for (int kt = 0; kt < 2; ++kt)
      bwb[nt][kt] =
          *(const bfrag*)(WTb + (nt * 16 + l15) * 64 + kt * 32 + q * 8);
  }
  __syncthreads();  // lds_st init visible before end-of-block atomics

  float sAcc[4] = {0.f, 0.f, 0.f, 0.f}, qAcc[4] = {0.f, 0.f, 0.f, 0.f};
  const size_t tbase = (size_t)blockIdx.x * TILES * 128;

  f4v xp;
  if (lane < 32) xp = *(const f4v*)(x + (tbase + wr + lane) * 4);

#pragma unroll
  for (int t = 0; t < TILES; ++t) {
    const size_t r0 = tbase + (size_t)t * 128;
    if (lane < 32) *(f4v*)&lds_x[(wr + lane) * 4] = xp;
    if (t + 1 < TILES && lane < 32)
      xp = *(const f4v*)(x + (r0 + 128 + wr + lane) * 4);

    // phase A: Y1 rows (wave-private)
    for (int e = 0; e < 32; ++e) {
      int row = wr + e;
      float acc = b0c;
#pragma unroll
      for (int k = 0; k < 4; ++k)
        acc = fmaf(fmaf(lds_x[row * 4 + k], sc0[k], sh0[k]), w0c[k], acc);
      float z = tanh_fast(acc);
      lds_y[row * 72 + lane] = f2bf(fmaf(A1c, z, B1c));
    }

    // phase B: A-frags (own rows), store Y1, stats matmul
    bfrag af[2][2];
#pragma unroll
    for (int mt = 0; mt < 2; ++mt)
#pragma unroll
      for (int kt = 0; kt < 2; ++kt) {
        af[mt][kt] =
            *(const bfrag*)&lds_y[(wr + mt * 16 + l15) * 72 + kt * 32 + q * 8];
        *(bfrag*)(Y + (r0 + wr + mt * 16 + l15) * 64 + kt * 32 + q * 8) =
            af[mt][kt];
      }
    facc acc2[2][4];
#pragma unroll
    for (int mt = 0; mt < 2; ++mt)
#pragma unroll
      for (int nt = 0; nt < 4; ++nt) {
        acc2[mt][nt][0] = bbv[nt]; acc2[mt][nt][1] = bbv[nt];
        acc2[mt][nt][2] = bbv[nt]; acc2[mt][nt][3] = bbv[nt];
      }
#pragma unroll
    for (int mt = 0; mt < 2; ++mt)
#pragma unroll
      for (int nt = 0; nt < 4; ++nt)
#pragma unroll
        for (int kt = 0; kt < 2; ++kt)
          acc2[mt][nt] = __builtin_amdgcn_mfma_f32_16x16x32_bf16(
              af[mt][kt], bwb[nt][kt], acc2[mt][nt], 0, 0, 0);
#pragma unroll
    for (int nt = 0; nt < 4; ++nt)
#pragma unroll
      for (int mt = 0; mt < 2; ++mt)
#pragma unroll
        for (int i = 0; i < 4; ++i) {
          float z = tanh_fast(acc2[mt][nt][i]);
          sAcc[nt] += z;
          qAcc[nt] = fmaf(z, z, qAcc[nt]);
        }
  }

#pragma unroll
  for (int nt = 0; nt < 4; ++nt) {
    float s = sAcc[nt], ss = qAcc[nt];
    s += __shfl_xor(s, 16); s += __shfl_xor(s, 32);
    ss += __shfl_xor(ss, 16); ss += __shfl_xor(ss, 32);
    if (q == 0) {
      atomicAdd(&lds_st[nt * 16 + l15], s);
      atomicAdd(&lds_st[64 + nt * 16 + l15], ss);
    }
  }
  __syncthreads();
  if (tid < 128) P[(size_t)blockIdx.x * 128 + tid] = lds_st[tid];
}

// K_mid: recompute Z_a = tanh(Y@WTa+ba), Ynew = BN(Z_a)+Y (in-place LDS),
// store Ynew; stats matmul with WTb -> P[bid][128]. Barrier-free tile loop.
__global__ __launch_bounds__(256, 3) void k_mid(
    short* __restrict__ Y, const short* __restrict__ WTa,
    const float* __restrict__ ba, const float* __restrict__ ga,
    const float* __restrict__ bea, const float* __restrict__ sa,
    const short* __restrict__ WTb, const float* __restrict__ bb,
    float* __restrict__ P) {
  __shared__ __align__(16) short lds_y[128 * 72];
  __shared__ float lds_st[128];

  const int tid = threadIdx.x;
  const int lane = tid & 63;
  const int wave = tid >> 6;
  const int l15 = lane & 15;
  const int q = lane >> 4;
  const int wr = wave * 32;

  if (tid < 128) lds_st[tid] = 0.f;
  // per-lane BN/bias constants for columns c = nt*16+l15
  float Av[4], Bv[4], bav[4], bbv[4];
#pragma unroll
  for (int nt = 0; nt < 4; ++nt) {
    int c = nt * 16 + l15;
    float mean = sa[c] * INV_B;
    float var = fmaf(-mean, mean, sa[64 + c] * INV_B);
    float A = ga[c] * rsqrtf(var + EPS);
    Av[nt] = A;
    Bv[nt] = fmaf(-A, mean, bea[c]);
    bav[nt] = ba[c];
    bbv[nt] = bb[c];
  }
  bfrag bwa[4][2], bwb[4][2];
#pragma unroll
  for (int nt = 0; nt < 4; ++nt)
#pragma unroll
    for (int kt = 0; kt < 2; ++kt) {
      bwa[nt][kt] =
          *(const bfrag*)(WTa + (nt * 16 + l15) * 64 + kt * 32 + q * 8);
      bwb[nt][kt] =
          *(const bfrag*)(WTb + (nt * 16 + l15) * 64 + kt * 32 + q * 8);
    }
  __syncthreads();  // lds_st init visible before end-of-block atomics

  float sAcc[4] = {0.f, 0.f, 0.f, 0.f}, qAcc[4] = {0.f, 0.f, 0.f, 0.f};
  const size_t tbase = (size_t)blockIdx.x * TILES * 128;
  const int srow = lane >> 3;         // 0..7
  const int sc8 = (lane & 7) * 8;     // staging col

  bfrag ld[4];
  {
    const size_t g = (tbase + wr + srow) * 64 + sc8;
#pragma unroll
    for (int it = 0; it < 4; ++it)
      ld[it] = *(const bfrag*)(Y + g + (size_t)it * 8 * 64);
  }

#pragma unroll
  for (int t = 0; t < TILES; ++t) {
    const size_t r0 = tbase + (size_t)t * 128;
    // stage own-wave rows
#pragma unroll
    for (int it = 0; it < 4; ++it)
      *(bfrag*)&lds_y[(wr + it * 8 + srow) * 72 + sc8] = ld[it];
    // prefetch next tile (flies during compute below)
    if (t + 1 < TILES) {
      const size_t g = (r0 + 128 + wr + srow) * 64 + sc8;
#pragma unroll
      for (int it = 0; it < 4; ++it)
        ld[it] = *(const bfrag*)(Y + g + (size_t)it * 8 * 64);
    }

    // matmul1: recompute Z_a (bit-identical to producer's stats matmul)
    bfrag af[2][2];
#pragma unroll
    for (int mt = 0; mt < 2; ++mt)
#pragma unroll
      for (int kt = 0; kt < 2; ++kt)
        af[mt][kt] =
            *(const bfrag*)&lds_y[(wr + mt * 16 + l15) * 72 + kt * 32 + q * 8];
    facc acc[2][4];
#pragma unroll
    for (int mt = 0; mt < 2; ++mt)
#pragma unroll
      for (int nt = 0; nt < 4; ++nt) {
        acc[mt][nt][0] = bav[nt]; acc[mt][nt][1] = bav[nt];
        acc[mt][nt][2] = bav[nt]; acc[mt][nt][3] = bav[nt];
      }
#pragma unroll
    for (int mt = 0; mt < 2; ++mt)
#pragma unroll
      for (int nt = 0; nt < 4; ++nt)
#pragma unroll
        for (int kt = 0; kt < 2; ++kt)
          acc[mt][nt] = __builtin_amdgcn_mfma_f32_16x16x32_bf16(
              af[mt][kt], bwa[nt][kt], acc[mt][nt], 0, 0, 0);

    // BN + residual, in-place (wave-private rows; owner-lane elements)
#pragma unroll
    for (int mt = 0; mt < 2; ++mt)
#pragma unroll
      for (int nt = 0; nt < 4; ++nt) {
        int c = nt * 16 + l15;
        float A = Av[nt], Bc = Bv[nt];
#pragma unroll
        for (int i = 0; i < 4; ++i) {
          int rl = wr + mt * 16 + q * 4 + i;
          float z = tanh_fast(acc[mt][nt][i]);
          float yo = bf2f(lds_y[rl * 72 + c]);
          lds_y[rl * 72 + c] = f2bf(fmaf(A, z, Bc) + yo);
        }
      }

    // phase 4: reload own rows (now Ynew), store, stats matmul
#pragma unroll
    for (int mt = 0; mt < 2; ++mt)
#pragma unroll
      for (int kt = 0; kt < 2; ++kt) {
        af[mt][kt] =
            *(const bfrag*)&lds_y[(wr + mt * 16 + l15) * 72 + kt * 32 + q * 8];
        *(bfrag*)(Y + (r0 + wr + mt * 16 + l15) * 64 + kt * 32 + q * 8) =
            af[mt][kt];
      }
#pragma unroll
    for (int mt = 0; mt < 2; ++mt)
#pragma unroll
      for (int nt = 0; nt < 4; ++nt) {
        acc[mt][nt][0] = bbv[nt]; acc[mt][nt][1] = bbv[nt];
        acc[mt][nt][2] = bbv[nt]; acc[mt][nt][3] = bbv[nt];
      }
#pragma unroll
    for (int mt = 0; mt < 2; ++mt)
#pragma unroll
      for (int nt = 0; nt < 4; ++nt)
#pragma unroll
        for (int kt = 0; kt < 2; ++kt)
          acc[mt][nt] = __builtin_amdgcn_mfma_f32_16x16x32_bf16(
              af[mt][kt], bwb[nt][kt], acc[mt][nt], 0, 0, 0);
#pragma unroll
    for (int nt = 0; nt < 4; ++nt)
#pragma unroll
      for (int mt = 0; mt < 2; ++mt)
#pragma unroll
        for (int i = 0; i < 4; ++i) {
          float z = tanh_fast(acc[mt][nt][i]);
          sAcc[nt] += z;
          qAcc[nt] = fmaf(z, z, qAcc[nt]);
        }
  }

#pragma unroll
  for (int nt = 0; nt < 4; ++nt) {
    float s = sAcc[nt], ss = qAcc[nt];
    s += __shfl_xor(s, 16); s += __shfl_xor(s, 32);
    ss += __shfl_xor(ss, 16); ss += __shfl_xor(ss, 32);
    if (q == 0) {
      atomicAdd(&lds_st[nt * 16 + l15], s);
      atomicAdd(&lds_st[64 + nt * 16 + l15], ss);
    }
  }
  __syncthreads();
  if (tid < 128) P[(size_t)blockIdx.x * 128 + tid] = lds_st[tid];
}

// K_last: recompute Z5, Y5 = BN(Z5)+Y4 (in-place), out = Y5 @ Wout + bout.
// Barrier-free: epilogue is wave-private (pair of lanes per row).
__global__ __launch_bounds__(256, 3) void k_last(
    const short* __restrict__ Y, const short* __restrict__ WTa,
    const float* __restrict__ ba, const float* __restrict__ ga,
    const float* __restrict__ bea, const float* __restrict__ sa,
    const float* __restrict__ Wout, const float* __restrict__ bout,
    float* __restrict__ out) {
  __shared__ __align__(16) short lds_y[128 * 72];
  __shared__ float lds_wo[192];

  const int tid = threadIdx.x;
  const int lane = tid & 63;
  const int wave = tid >> 6;
  const int l15 = lane & 15;
  const int q = lane >> 4;
  const int wr = wave * 32;

  if (tid < 192) lds_wo[tid] = Wout[tid];
  float Av[4], Bv[4], bav[4];
#pragma unroll
  for (int nt = 0; nt < 4; ++nt) {
    int c = nt * 16 + l15;
    float mean = sa[c] * INV_B;
    float var = fmaf(-mean, mean, sa[64 + c] * INV_B);
    float A = ga[c] * rsqrtf(var + EPS);
    Av[nt] = A;
    Bv[nt] = fmaf(-A, mean, bea[c]);
    bav[nt] = ba[c];
  }
  bfrag bwa[4][2];
#pragma unroll
  for (int nt = 0; nt < 4; ++nt)
#pragma unroll
    for (int kt = 0; kt < 2; ++kt)
      bwa[nt][kt] =
          *(const bfrag*)(WTa + (nt * 16 + l15) * 64 + kt * 32 + q * 8);
  float bo0 = bout[0], bo1 = bout[1], bo2 = bout[2];
  __syncthreads();  // lds_wo

  const size_t tbase = (size_t)blockIdx.x * TILES * 128;
  const int srow = lane >> 3;
  const int sc8 = (lane & 7) * 8;

  bfrag ld[4];
  {
    const size_t g = (tbase + wr + srow) * 64 + sc8;
#pragma unroll
    for (int it = 0; it < 4; ++it)
      ld[it] = *(const bfrag*)(Y + g + (size_t)it * 8 * 64);
  }

#pragma unroll
  for (int t = 0; t < TILES; ++t) {
    const size_t r0 = tbase + (size_t)t * 128;
#pragma unroll
    for (int it = 0; it < 4; ++it)
      *(bfrag*)&lds_y[(wr + it * 8 + srow) * 72 + sc8] = ld[it];
    if (t + 1 < TILES) {
      const size_t g = (r0 + 128 + wr + srow) * 64 + sc8;
#pragma unroll
      for (int it = 0; it < 4; ++it)
        ld[it] = *(const bfrag*)(Y + g + (size_t)it * 8 * 64);
    }

    bfrag af[2][2];
#pragma unroll
    for (int mt = 0; mt < 2; ++mt)
#pragma unroll
      for (int kt = 0; kt < 2; ++kt)
        af[mt][kt] =
            *(const bfrag*)&lds_y[(wr + mt * 16 + l15) * 72 + kt * 32 + q * 8];
    facc acc[2][4];
#pragma unroll
    for (int mt = 0; mt < 2; ++mt)
#pragma unroll
      for (int nt = 0; nt < 4; ++nt) {
        acc[mt][nt][0] = bav[nt]; acc[mt][nt][1] = bav[nt];
        acc[mt][nt][2] = bav[nt]; acc[mt][nt][3] = bav[nt];
      }
#pragma unroll
    for (int mt = 0; mt < 2; ++mt)
#pragma unroll
      for (int nt = 0; nt < 4; ++nt)
#pragma unroll
        for (int kt = 0; kt < 2; ++kt)
          acc[mt][nt] = __builtin_amdgcn_mfma_f32_16x16x32_bf16(
              af[mt][kt], bwa[nt][kt], acc[mt][nt], 0, 0, 0);
#pragma unroll
    for (int mt = 0; mt < 2; ++mt)
#pragma unroll
      for (int nt = 0; nt < 4; ++nt) {
        int c = nt * 16 + l15;
        float A = Av[nt], Bc = Bv[nt];
#pragma unroll
        for (int i = 0; i < 4; ++i) {
          int rl = wr + mt * 16 + q * 4 + i;
          float z = tanh_fast(acc[mt][nt][i]);
          float yo = bf2f(lds_y[rl * 72 + c]);
          lds_y[rl * 72 + c] = f2bf(fmaf(A, z, Bc) + yo);
        }
      }

    // epilogue (wave-private): lane pair (2r,2r+1) handles row wr+r
    {
      int row = wr + (lane >> 1);
      int cb = (lane & 1) * 32;
      float o0 = 0.f, o1 = 0.f, o2 = 0.f;
#pragma unroll
      for (int jc = 0; jc < 4; ++jc) {
        bfrag v = *(const bfrag*)&lds_y[row * 72 + cb + jc * 8];
#pragma unroll
        for (int j = 0; j < 8; ++j) {
          float f = bf2f(v[j]);
          int jj = cb + jc * 8 + j;
          o0 = fmaf(f, lds_wo[jj * 3 + 0], o0);
          o1 = fmaf(f, lds_wo[jj * 3 + 1], o1);
          o2 = fmaf(f, lds_wo[jj * 3 + 2], o2);
        }
      }
      o0 += __shfl_xor(o0, 1);
      o1 += __shfl_xor(o1, 1);
      o2 += __shfl_xor(o2, 1);
      if ((lane & 1) == 0) {
        size_t ro = (r0 + row) * 3;
        out[ro] = o0 + bo0;
        out[ro + 1] = o1 + bo1;
        out[ro + 2] = o2 + bo2;
      }
    }
  }
}

extern "C" void kernel_launch(void* const* d_in, const int* in_sizes, int n_in,
                              void* d_out, int out_size, void* d_ws,
                              size_t ws_size, hipStream_t stream) {
  (void)in_sizes; (void)n_in; (void)out_size; (void)ws_size;
  const float* x = (const float*)d_in[0];
  const float* bn0g = (const float*)d_in[1];
  const float* bn0b = (const float*)d_in[2];
  const float* W0 = (const float*)d_in[3];
  const float* b0 = (const float*)d_in[4];
  const float* gamma0 = (const float*)d_in[5];
  const float* beta0 = (const float*)d_in[6];
  const float* Wh = (const float*)d_in[7];
  const float* bh = (const float*)d_in[8];
  const float* gh = (const float*)d_in[9];
  const float* beh = (const float*)d_in[10];
  const float* Wout = (const float*)d_in[11];
  const float* bout = (const float*)d_in[12];
  float* out = (float*)d_out;

  char* ws = (char*)d_ws;
  short* Y = (short*)ws;                       // 1M x 64 bf16 = 128 MB
  const size_t YB = (size_t)NROWS * 64 * 2;
  float* stats = (float*)(ws + YB);            // [Sx 8][S1..S5 128 each]
  float* Sx = stats;
  float* S1 = stats + 8;
  float* S2 = stats + 136;
  float* S3 = stats + 264;
  float* S4 = stats + 392;
  float* S5 = stats + 520;
  short* WT = (short*)(ws + YB + 4096);        // 4 x 64 x 64 bf16 = 32 KB
  float* P = (float*)(ws + YB + 4096 + 32768); // partials: <= 2048x128 f32 = 1 MB

  hipMemsetAsync(stats, 0, 648 * sizeof(float), stream);
  k_prep<<<64, 256, 0, stream>>>(Wh, WT);
  k_stats_x<<<1024, 256, 0, stream>>>(x, P);
  k_reduce<8><<<8, 256, 0, stream>>>(P, Sx, 128);
  k_stats_z1<<<1024, 256, 0, stream>>>(x, bn0g, bn0b, W0, b0, Sx, P);
  k_reduce<128><<<8, 256, 0, stream>>>(P, S1, 128);
  k_first<<<BIGGRID, 256, 0, stream>>>(x, bn0g, bn0b, W0, b0, gamma0, beta0,
                                       Sx, S1, WT, bh, P, Y);
  k_reduce<128><<<16, 256, 0, stream>>>(P, S2, 128);
  k_mid<<<BIGGRID, 256, 0, stream>>>(Y, WT, bh, gh, beh, S2, WT + 4096,
                                     bh + 64, P);
  k_reduce<128><<<16, 256, 0, stream>>>(P, S3, 128);
  k_mid<<<BIGGRID, 256, 0, stream>>>(Y, WT + 4096, bh + 64, gh + 64, beh + 64,
                                     S3, WT + 2 * 4096, bh + 128, P);
  k_reduce<128><<<16, 256, 0, stream>>>(P, S4, 128);
  k_mid<<<BIGGRID, 256, 0, stream>>>(Y, WT + 2 * 4096, bh + 128, gh + 128,
                                     beh + 128, S4, WT + 3 * 4096, bh + 192, P);
  k_reduce<128><<<16, 256, 0, stream>>>(P, S5, 128);
  k_last<<<BIGGRID, 256, 0, stream>>>(Y, WT + 3 * 4096, bh + 192, gh + 192,
                                      beh + 192, S5, Wout, bout, out);
}

// Round 4
// 562.429 us; speedup vs baseline: 1.0671x; 1.0671x over previous
//
#include <hip/hip_runtime.h>
#include <stdint.h>

// B = 1048576 rows, HID = 64. Residual MLP with training-mode BatchNorm.
// Recompute-fused layer kernels + bf16 activations (128 MB in d_ws).
// Round 4: R2 memory structure (1 tile/block) with 128-thread blocks /
// 64-row tiles (grid 16384) for finer scheduling granularity; staging loads
// issued before constant setup; stats B-frags loaded late.
// MFMA 16x16x32 bf16 layouts (verified gfx950 mappings):
//   A: row = lane&15, k = (lane>>4)*8 + j   (16B contiguous -> b128)
//   B: col = lane&15, k = (lane>>4)*8 + j   (load from W^T, row-major)
//   C/D: col = lane&15, row = (lane>>4)*4 + reg

#define NROWS 1048576
#define EPS 1e-5f
#define INV_B 9.5367431640625e-07f  // 1/2^20 exact
#define LOG2E2 2.885390081777927f   // 2*log2(e)
#define BIGGRID 16384               // 16384 blocks x 64 rows

typedef __attribute__((ext_vector_type(8))) short bfrag;   // 8 bf16 = 4 VGPR
typedef __attribute__((ext_vector_type(4))) float facc;    // MFMA C/D
typedef __attribute__((ext_vector_type(4))) float f4v;

__device__ __forceinline__ float bf2f(short s) {
  union { unsigned u; float f; } v;
  v.u = ((unsigned)(unsigned short)s) << 16;
  return v.f;
}
__device__ __forceinline__ short f2bf(float f) {
  union { float f; unsigned u; } v;
  v.f = f;
  unsigned r = v.u + 0x7FFFu + ((v.u >> 16) & 1u);  // RNE
  return (short)(r >> 16);
}
// tanh = 1 - 2/(e^{2x}+1); v_exp + v_rcp, saturates correctly at +-inf
__device__ __forceinline__ float tanh_fast(float x) {
  float e = __builtin_amdgcn_exp2f(x * LOG2E2);
  return 1.f - 2.f * __builtin_amdgcn_rcpf(e + 1.f);
}

// ---------------- reduce: P[nb][W] -> atomicAdd into S[W] ----------------
template <int W>
__global__ __launch_bounds__(256) void k_reduce(const float* __restrict__ P,
                                                float* __restrict__ S,
                                                int rows_per_blk) {
  __shared__ float red[256];
  const int tid = threadIdx.x;
  const int col = tid % W;
  const int grp = tid / W;
  const int G = 256 / W;
  size_t r0 = (size_t)blockIdx.x * rows_per_blk;
  float s = 0.f;
  for (int r = grp; r < rows_per_blk; r += G) s += P[(r0 + r) * W + col];
  red[tid] = s;
  __syncthreads();
  if (tid < W) {
    float t = 0.f;
#pragma unroll 4
    for (int g = 0; g < G; ++g) t += red[g * W + tid];
    atomicAdd(&S[tid], t);
  }
}

// ---------------- small kernels ----------------

__global__ __launch_bounds__(256) void k_stats_x(const float* __restrict__ x,
                                                 float* __restrict__ P) {
  __shared__ float red[4][8];
  const int tid = threadIdx.x;
  const int wave = tid >> 6;
  size_t base = (size_t)blockIdx.x * 1024 + tid;
  float s[4] = {0.f, 0.f, 0.f, 0.f}, q[4] = {0.f, 0.f, 0.f, 0.f};
#pragma unroll
  for (int it = 0; it < 4; ++it) {
    f4v v = *(const f4v*)(x + (base + (size_t)it * 256) * 4);
#pragma unroll
    for (int k = 0; k < 4; ++k) { s[k] += v[k]; q[k] = fmaf(v[k], v[k], q[k]); }
  }
#pragma unroll
  for (int off = 32; off > 0; off >>= 1) {
#pragma unroll
    for (int k = 0; k < 4; ++k) {
      s[k] += __shfl_xor(s[k], off);
      q[k] += __shfl_xor(q[k], off);
    }
  }
  if ((tid & 63) == 0) {
#pragma unroll
    for (int k = 0; k < 4; ++k) { red[wave][k] = s[k]; red[wave][4 + k] = q[k]; }
  }
  __syncthreads();
  if (tid < 8)
    P[blockIdx.x * 8 + tid] =
        red[0][tid] + red[1][tid] + red[2][tid] + red[3][tid];
}

__global__ __launch_bounds__(256) void k_stats_z1(
    const float* __restrict__ x, const float* __restrict__ bn0g,
    const float* __restrict__ bn0b, const float* __restrict__ W0,
    const float* __restrict__ b0, const float* __restrict__ sx,
    float* __restrict__ P) {
  __shared__ float red[2][4][64];
  const int tid = threadIdx.x;
  const int lane = tid & 63;
  const int wave = tid >> 6;
  int gw = blockIdx.x * 4 + wave;
  float sc[4], sh[4];
#pragma unroll
  for (int k = 0; k < 4; ++k) {
    float mean = sx[k] * INV_B;
    float var = fmaf(-mean, mean, sx[4 + k] * INV_B);
    float rs = rsqrtf(var + EPS);
    sc[k] = bn0g[k] * rs;
    sh[k] = fmaf(-sc[k], mean, bn0b[k]);
  }
  float w[4];
#pragma unroll
  for (int k = 0; k < 4; ++k) w[k] = W0[k * 64 + lane];
  float bj = b0[lane];
  float s = 0.f, q = 0.f;
  size_t r0 = (size_t)gw * 256;
  for (int r = 0; r < 256; ++r) {
    f4v xv = *(const f4v*)(x + (r0 + r) * 4);
    float acc = bj;
#pragma unroll
    for (int k = 0; k < 4; ++k)
      acc = fmaf(fmaf(xv[k], sc[k], sh[k]), w[k], acc);
    float z = tanh_fast(acc);
    s += z;
    q = fmaf(z, z, q);
  }
  red[0][wave][lane] = s;
  red[1][wave][lane] = q;
  __syncthreads();
  if (tid < 128) {
    int which = tid >> 6, c = tid & 63;
    P[blockIdx.x * 128 + tid] = red[which][0][c] + red[which][1][c] +
                                red[which][2][c] + red[which][3][c];
  }
}

__global__ __launch_bounds__(256) void k_prep(const float* __restrict__ Wh,
                                              short* __restrict__ WT) {
  int idx = blockIdx.x * 256 + threadIdx.x;  // 16384 total
  int l = idx >> 12, rem = idx & 4095, k = rem >> 6, c = rem & 63;
  WT[l * 4096 + c * 64 + k] = f2bf(Wh[l * 4096 + k * 64 + c]);
}

// ---------------- big fused kernels: 64 rows/block, 2 waves of 32 rows ----

// K_first: Y1 = BN(tanh(bn0(x)@W0+b0)), write Y1 bf16,
// partial stats of Z2 = tanh(Y1 @ W_hid0 + b_hid0) -> P[bid][128]
__global__ __launch_bounds__(128) void k_first(
    const float* __restrict__ x, const float* __restrict__ bn0g,
    const float* __restrict__ bn0b, const float* __restrict__ W0,
    const float* __restrict__ b0, const float* __restrict__ gamma0,
    const float* __restrict__ beta0, const float* __restrict__ sx,
    const float* __restrict__ s1, const short* __restrict__ WTb,
    const float* __restrict__ bb, float* __restrict__ P,
    short* __restrict__ Y) {
  __shared__ __align__(16) float lds_x[64 * 4];
  __shared__ __align__(16) short lds_y[64 * 72];
  __shared__ float lds_st[128];

  const int tid = threadIdx.x;
  const int lane = tid & 63;
  const int wave = tid >> 6;
  const int l15 = lane & 15;
  const int q = lane >> 4;
  const int wr = wave * 32;
  const size_t r0 = (size_t)blockIdx.x * 64;

  // x staging load first (in flight during constant setup)
  f4v xp;
  if (lane < 32) xp = *(const f4v*)(x + (r0 + wr + lane) * 4);

  lds_st[tid] = 0.f;
  float sc0[4], sh0[4];
#pragma unroll
  for (int k = 0; k < 4; ++k) {
    float mean = sx[k] * INV_B;
    float var = fmaf(-mean, mean, sx[4 + k] * INV_B);
    float rs = rsqrtf(var + EPS);
    sc0[k] = bn0g[k] * rs;
    sh0[k] = fmaf(-sc0[k], mean, bn0b[k]);
  }
  float w0c[4];
#pragma unroll
  for (int k = 0; k < 4; ++k) w0c[k] = W0[k * 64 + lane];
  float b0c = b0[lane];
  float mean1 = s1[lane] * INV_B;
  float var1 = fmaf(-mean1, mean1, s1[64 + lane] * INV_B);
  float A1c = gamma0[lane] * rsqrtf(var1 + EPS);
  float B1c = fmaf(-A1c, mean1, beta0[lane]);
  if (lane < 32) *(f4v*)&lds_x[(wr + lane) * 4] = xp;
  __syncthreads();  // lds_st init (atomics later) + lds_x not strictly needed
                    // cross-wave but cheap

  // phase A: Y1 rows (wave-private)
  for (int e = 0; e < 32; ++e) {
    int row = wr + e;
    float acc = b0c;
#pragma unroll
    for (int k = 0; k < 4; ++k)
      acc = fmaf(fmaf(lds_x[row * 4 + k], sc0[k], sh0[k]), w0c[k], acc);
    float z = tanh_fast(acc);
    lds_y[row * 72 + lane] = f2bf(fmaf(A1c, z, B1c));
  }

  // phase B: A-frags (own rows), store Y1, stats matmul
  bfrag af[2][2];
#pragma unroll
  for (int mt = 0; mt < 2; ++mt)
#pragma unroll
    for (int kt = 0; kt < 2; ++kt) {
      af[mt][kt] =
          *(const bfrag*)&lds_y[(wr + mt * 16 + l15) * 72 + kt * 32 + q * 8];
      *(bfrag*)(Y + (r0 + wr + mt * 16 + l15) * 64 + kt * 32 + q * 8) =
          af[mt][kt];
    }
  float bbv[4];
  bfrag bwb[4][2];
#pragma unroll
  for (int nt = 0; nt < 4; ++nt) {
    bbv[nt] = bb[nt * 16 + l15];
#pragma unroll
    for (int kt = 0; kt < 2; ++kt)
      bwb[nt][kt] =
          *(const bfrag*)(WTb + (nt * 16 + l15) * 64 + kt * 32 + q * 8);
  }
  facc acc2[2][4];
#pragma unroll
  for (int mt = 0; mt < 2; ++mt)
#pragma unroll
    for (int nt = 0; nt < 4; ++nt) {
      acc2[mt][nt][0] = bbv[nt]; acc2[mt][nt][1] = bbv[nt];
      acc2[mt][nt][2] = bbv[nt]; acc2[mt][nt][3] = bbv[nt];
    }
#pragma unroll
  for (int mt = 0; mt < 2; ++mt)
#pragma unroll
    for (int nt = 0; nt < 4; ++nt)
#pragma unroll
      for (int kt = 0; kt < 2; ++kt)
        acc2[mt][nt] = __builtin_amdgcn_mfma_f32_16x16x32_bf16(
            af[mt][kt], bwb[nt][kt], acc2[mt][nt], 0, 0, 0);
  float sAcc[4], qAcc[4];
#pragma unroll
  for (int nt = 0; nt < 4; ++nt) {
    sAcc[nt] = 0.f;
    qAcc[nt] = 0.f;
#pragma unroll
    for (int mt = 0; mt < 2; ++mt)
#pragma unroll
      for (int i = 0; i < 4; ++i) {
        float z = tanh_fast(acc2[mt][nt][i]);
        sAcc[nt] += z;
        qAcc[nt] = fmaf(z, z, qAcc[nt]);
      }
    float s = sAcc[nt], ss = qAcc[nt];
    s += __shfl_xor(s, 16); s += __shfl_xor(s, 32);
    ss += __shfl_xor(ss, 16); ss += __shfl_xor(ss, 32);
    if (q == 0) {
      atomicAdd(&lds_st[nt * 16 + l15], s);
      atomicAdd(&lds_st[64 + nt * 16 + l15], ss);
    }
  }
  __syncthreads();
  P[(size_t)blockIdx.x * 128 + tid] = lds_st[tid];
}

// K_mid: recompute Z_a = tanh(Y@WTa+ba), Ynew = BN(Z_a)+Y (in-place LDS),
// store Ynew; stats matmul with WTb -> P[bid][128].
__global__ __launch_bounds__(128) void k_mid(
    short* __restrict__ Y, const short* __restrict__ WTa,
    const float* __restrict__ ba, const float* __restrict__ ga,
    const float* __restrict__ bea, const float* __restrict__ sa,
    const short* __restrict__ WTb, const float* __restrict__ bb,
    float* __restrict__ P) {
  __shared__ __align__(16) short lds_y[64 * 72];
  __shared__ float lds_st[128];

  const int tid = threadIdx.x;
  const int lane = tid & 63;
  const int wave = tid >> 6;
  const int l15 = lane & 15;
  const int q = lane >> 4;
  const int wr = wave * 32;
  const size_t r0 = (size_t)blockIdx.x * 64;
  const int srow = lane >> 3;       // 0..7
  const int sc8 = (lane & 7) * 8;   // staging col

  // staging loads FIRST (fly during constant setup)
  bfrag ld[4];
  {
    const size_t g = (r0 + wr + srow) * 64 + sc8;
#pragma unroll
    for (int it = 0; it < 4; ++it)
      ld[it] = *(const bfrag*)(Y + g + (size_t)it * 8 * 64);
  }

  lds_st[tid] = 0.f;
  float Av[4], Bv[4], bav[4];
#pragma unroll
  for (int nt = 0; nt < 4; ++nt) {
    int c = nt * 16 + l15;
    float mean = sa[c] * INV_B;
    float var = fmaf(-mean, mean, sa[64 + c] * INV_B);
    float A = ga[c] * rsqrtf(var + EPS);
    Av[nt] = A;
    Bv[nt] = fmaf(-A, mean, bea[c]);
    bav[nt] = ba[c];
  }
  bfrag bwa[4][2];
#pragma unroll
  for (int nt = 0; nt < 4; ++nt)
#pragma unroll
    for (int kt = 0; kt < 2; ++kt)
      bwa[nt][kt] =
          *(const bfrag*)(WTa + (nt * 16 + l15) * 64 + kt * 32 + q * 8);

  // stage own-wave rows
#pragma unroll
  for (int it = 0; it < 4; ++it)
    *(bfrag*)&lds_y[(wr + it * 8 + srow) * 72 + sc8] = ld[it];
  __syncthreads();  // lds_st init visible before end-of-block atomics

  // matmul1: recompute Z_a (bit-identical to producer's stats matmul)
  bfrag af[2][2];
#pragma unroll
  for (int mt = 0; mt < 2; ++mt)
#pragma unroll
    for (int kt = 0; kt < 2; ++kt)
      af[mt][kt] =
          *(const bfrag*)&lds_y[(wr + mt * 16 + l15) * 72 + kt * 32 + q * 8];
  facc acc[2][4];
#pragma unroll
  for (int mt = 0; mt < 2; ++mt)
#pragma unroll
    for (int nt = 0; nt < 4; ++nt) {
      acc[mt][nt][0] = bav[nt]; acc[mt][nt][1] = bav[nt];
      acc[mt][nt][2] = bav[nt]; acc[mt][nt][3] = bav[nt];
    }
#pragma unroll
  for (int mt = 0; mt < 2; ++mt)
#pragma unroll
    for (int nt = 0; nt < 4; ++nt)
#pragma unroll
      for (int kt = 0; kt < 2; ++kt)
        acc[mt][nt] = __builtin_amdgcn_mfma_f32_16x16x32_bf16(
            af[mt][kt], bwa[nt][kt], acc[mt][nt], 0, 0, 0);

  // BN + residual, in-place (wave-private rows; owner-lane elements)
#pragma unroll
  for (int mt = 0; mt < 2; ++mt)
#pragma unroll
    for (int nt = 0; nt < 4; ++nt) {
      int c = nt * 16 + l15;
      float A = Av[nt], Bc = Bv[nt];
#pragma unroll
      for (int i = 0; i < 4; ++i) {
        int rl = wr + mt * 16 + q * 4 + i;
        float z = tanh_fast(acc[mt][nt][i]);
        float yo = bf2f(lds_y[rl * 72 + c]);
        lds_y[rl * 72 + c] = f2bf(fmaf(A, z, Bc) + yo);
      }
    }

  // phase 4: reload own rows (now Ynew), store; stats matmul with late bwb
#pragma unroll
  for (int mt = 0; mt < 2; ++mt)
#pragma unroll
    for (int kt = 0; kt < 2; ++kt) {
      af[mt][kt] =
          *(const bfrag*)&lds_y[(wr + mt * 16 + l15) * 72 + kt * 32 + q * 8];
      *(bfrag*)(Y + (r0 + wr + mt * 16 + l15) * 64 + kt * 32 + q * 8) =
          af[mt][kt];
    }
  float bbv[4];
  bfrag bwb[4][2];
#pragma unroll
  for (int nt = 0; nt < 4; ++nt) {
    bbv[nt] = bb[nt * 16 + l15];
#pragma unroll
    for (int kt = 0; kt < 2; ++kt)
      bwb[nt][kt] =
          *(const bfrag*)(WTb + (nt * 16 + l15) * 64 + kt * 32 + q * 8);
  }
#pragma unroll
  for (int mt = 0; mt < 2; ++mt)
#pragma unroll
    for (int nt = 0; nt < 4; ++nt) {
      acc[mt][nt][0] = bbv[nt]; acc[mt][nt][1] = bbv[nt];
      acc[mt][nt][2] = bbv[nt]; acc[mt][nt][3] = bbv[nt];
    }
#pragma unroll
  for (int mt = 0; mt < 2; ++mt)
#pragma unroll
    for (int nt = 0; nt < 4; ++nt)
#pragma unroll
      for (int kt = 0; kt < 2; ++kt)
        acc[mt][nt] = __builtin_amdgcn_mfma_f32_16x16x32_bf16(
            af[mt][kt], bwb[nt][kt], acc[mt][nt], 0, 0, 0);
#pragma unroll
  for (int nt = 0; nt < 4; ++nt) {
    float s = 0.f, ss = 0.f;
#pragma unroll
    for (int mt = 0; mt < 2; ++mt)
#pragma unroll
      for (int i = 0; i < 4; ++i) {
        float z = tanh_fast(acc[mt][nt][i]);
        s += z;
        ss = fmaf(z, z, ss);
      }
    s += __shfl_xor(s, 16); s += __shfl_xor(s, 32);
    ss += __shfl_xor(ss, 16); ss += __shfl_xor(ss, 32);
    if (q == 0) {
      atomicAdd(&lds_st[nt * 16 + l15], s);
      atomicAdd(&lds_st[64 + nt * 16 + l15], ss);
    }
  }
  __syncthreads();
  P[(size_t)blockIdx.x * 128 + tid] = lds_st[tid];
}

// K_last: recompute Z5, Y5 = BN(Z5)+Y4 (in-place), out = Y5 @ Wout + bout.
__global__ __launch_bounds__(128) void k_last(
    const short* __restrict__ Y, const short* __restrict__ WTa,
    const float* __restrict__ ba, const float* __restrict__ ga,
    const float* __restrict__ bea, const float* __restrict__ sa,
    const float* __restrict__ Wout, const float* __restrict__ bout,
    float* __restrict__ out) {
  __shared__ __align__(16) short lds_y[64 * 72];
  __shared__ float lds_wo[192];

  const int tid = threadIdx.x;
  const int lane = tid & 63;
  const int wave = tid >> 6;
  const int l15 = lane & 15;
  const int q = lane >> 4;
  const int wr = wave * 32;
  const size_t r0 = (size_t)blockIdx.x * 64;
  const int srow = lane >> 3;
  const int sc8 = (lane & 7) * 8;

  bfrag ld[4];
  {
    const size_t g = (r0 + wr + srow) * 64 + sc8;
#pragma unroll
    for (int it = 0; it < 4; ++it)
      ld[it] = *(const bfrag*)(Y + g + (size_t)it * 8 * 64);
  }

  for (int i = tid; i < 192; i += 128) lds_wo[i] = Wout[i];
  float Av[4], Bv[4], bav[4];
#pragma unroll
  for (int nt = 0; nt < 4; ++nt) {
    int c = nt * 16 + l15;
    float mean = sa[c] * INV_B;
    float var = fmaf(-mean, mean, sa[64 + c] * INV_B);
    float A = ga[c] * rsqrtf(var + EPS);
    Av[nt] = A;
    Bv[nt] = fmaf(-A, mean, bea[c]);
    bav[nt] = ba[c];
  }
  bfrag bwa[4][2];
#pragma unroll
  for (int nt = 0; nt < 4; ++nt)
#pragma unroll
    for (int kt = 0; kt < 2; ++kt)
      bwa[nt][kt] =
          *(const bfrag*)(WTa + (nt * 16 + l15) * 64 + kt * 32 + q * 8);
  float bo0 = bout[0], bo1 = bout[1], bo2 = bout[2];

#pragma unroll
  for (int it = 0; it < 4; ++it)
    *(bfrag*)&lds_y[(wr + it * 8 + srow) * 72 + sc8] = ld[it];
  __syncthreads();  // lds_wo

  bfrag af[2][2];
#pragma unroll
  for (int mt = 0; mt < 2; ++mt)
#pragma unroll
    for (int kt = 0; kt < 2; ++kt)
      af[mt][kt] =
          *(const bfrag*)&lds_y[(wr + mt * 16 + l15) * 72 + kt * 32 + q * 8];
  facc acc[2][4];
#pragma unroll
  for (int mt = 0; mt < 2; ++mt)
#pragma unroll
    for (int nt = 0; nt < 4; ++nt) {
      acc[mt][nt][0] = bav[nt]; acc[mt][nt][1] = bav[nt];
      acc[mt][nt][2] = bav[nt]; acc[mt][nt][3] = bav[nt];
    }
#pragma unroll
  for (int mt = 0; mt < 2; ++mt)
#pragma unroll
    for (int nt = 0; nt < 4; ++nt)
#pragma unroll
      for (int kt = 0; kt < 2; ++kt)
        acc[mt][nt] = __builtin_amdgcn_mfma_f32_16x16x32_bf16(
            af[mt][kt], bwa[nt][kt], acc[mt][nt], 0, 0, 0);
#pragma unroll
  for (int mt = 0; mt < 2; ++mt)
#pragma unroll
    for (int nt = 0; nt < 4; ++nt) {
      int c = nt * 16 + l15;
      float A = Av[nt], Bc = Bv[nt];
#pragma unroll
      for (int i = 0; i < 4; ++i) {
        int rl = wr + mt * 16 + q * 4 + i;
        float z = tanh_fast(acc[mt][nt][i]);
        float yo = bf2f(lds_y[rl * 72 + c]);
        lds_y[rl * 72 + c] = f2bf(fmaf(A, z, Bc) + yo);
      }
    }

  // epilogue (wave-private): lane pair (2r,2r+1) handles row wr+r
  {
    int row = wr + (lane >> 1);
    int cb = (lane & 1) * 32;
    float o0 = 0.f, o1 = 0.f, o2 = 0.f;
#pragma unroll
    for (int jc = 0; jc < 4; ++jc) {
      bfrag v = *(const bfrag*)&lds_y[row * 72 + cb + jc * 8];
#pragma unroll
      for (int j = 0; j < 8; ++j) {
        float f = bf2f(v[j]);
        int jj = cb + jc * 8 + j;
        o0 = fmaf(f, lds_wo[jj * 3 + 0], o0);
        o1 = fmaf(f, lds_wo[jj * 3 + 1], o1);
        o2 = fmaf(f, lds_wo[jj * 3 + 2], o2);
      }
    }
    o0 += __shfl_xor(o0, 1);
    o1 += __shfl_xor(o1, 1);
    o2 += __shfl_xor(o2, 1);
    if ((lane & 1) == 0) {
      size_t ro = (r0 + row) * 3;
      out[ro] = o0 + bo0;
      out[ro + 1] = o1 + bo1;
      out[ro + 2] = o2 + bo2;
    }
  }
}

extern "C" void kernel_launch(void* const* d_in, const int* in_sizes, int n_in,
                              void* d_out, int out_size, void* d_ws,
                              size_t ws_size, hipStream_t stream) {
  (void)in_sizes; (void)n_in; (void)out_size; (void)ws_size;
  const float* x = (const float*)d_in[0];
  const float* bn0g = (const float*)d_in[1];
  const float* bn0b = (const float*)d_in[2];
  const float* W0 = (const float*)d_in[3];
  const float* b0 = (const float*)d_in[4];
  const float* gamma0 = (const float*)d_in[5];
  const float* beta0 = (const float*)d_in[6];
  const float* Wh = (const float*)d_in[7];
  const float* bh = (const float*)d_in[8];
  const float* gh = (const float*)d_in[9];
  const float* beh = (const float*)d_in[10];
  const float* Wout = (const float*)d_in[11];
  const float* bout = (const float*)d_in[12];
  float* out = (float*)d_out;

  char* ws = (char*)d_ws;
  short* Y = (short*)ws;                       // 1M x 64 bf16 = 128 MB
  const size_t YB = (size_t)NROWS * 64 * 2;
  float* stats = (float*)(ws + YB);            // [Sx 8][S1..S5 128 each]
  float* Sx = stats;
  float* S1 = stats + 8;
  float* S2 = stats + 136;
  float* S3 = stats + 264;
  float* S4 = stats + 392;
  float* S5 = stats + 520;
  short* WT = (short*)(ws + YB + 4096);        // 4 x 64 x 64 bf16 = 32 KB
  float* P = (float*)(ws + YB + 4096 + 32768); // partials: 16384x128 f32 = 8 MB

  hipMemsetAsync(stats, 0, 648 * sizeof(float), stream);
  k_prep<<<64, 256, 0, stream>>>(Wh, WT);
  k_stats_x<<<1024, 256, 0, stream>>>(x, P);
  k_reduce<8><<<8, 256, 0, stream>>>(P, Sx, 128);
  k_stats_z1<<<1024, 256, 0, stream>>>(x, bn0g, bn0b, W0, b0, Sx, P);
  k_reduce<128><<<8, 256, 0, stream>>>(P, S1, 128);
  k_first<<<BIGGRID, 128, 0, stream>>>(x, bn0g, bn0b, W0, b0, gamma0, beta0,
                                       Sx, S1, WT, bh, P, Y);
  k_reduce<128><<<128, 256, 0, stream>>>(P, S2, 128);
  k_mid<<<BIGGRID, 128, 0, stream>>>(Y, WT, bh, gh, beh, S2, WT + 4096,
                                     bh + 64, P);
  k_reduce<128><<<128, 256, 0, stream>>>(P, S3, 128);
  k_mid<<<BIGGRID, 128, 0, stream>>>(Y, WT + 4096, bh + 64, gh + 64, beh + 64,
                                     S3, WT + 2 * 4096, bh + 128, P);
  k_reduce<128><<<128, 256, 0, stream>>>(P, S4, 128);
  k_mid<<<BIGGRID, 128, 0, stream>>>(Y, WT + 2 * 4096, bh + 128, gh + 128,
                                     beh + 128, S4, WT + 3 * 4096, bh + 192, P);
  k_reduce<128><<<128, 256, 0, stream>>>(P, S5, 128);
  k_last<<<BIGGRID, 128, 0, stream>>>(Y, WT + 3 * 4096, bh + 192, gh + 192,
                                      beh + 192, S5, Wout, bout, out);
}